// Round 3
// baseline (1584.043 us; speedup 1.0000x reference)
//
#include <hip/hip_runtime.h>
#include <hip/hip_bf16.h>
#include <math.h>

#define B_ 8
#define L_ 2048
#define E_ 100
#define F_ 256
#define Y_ 8921
#define YP 8960      // Y padded to 70*128
#define KC 928       // conv K padded: 9*100=900 -> 928 (29 K-steps of 32)
#define MC 16384     // B*L

#define VMCNT(n) asm volatile("s_waitcnt vmcnt(" #n ")" ::: "memory")
#define LGKM0() asm volatile("s_waitcnt lgkmcnt(0)" ::: "memory")
#define CFENCE() asm volatile("" ::: "memory")

typedef __bf16 bf16x8 __attribute__((ext_vector_type(8)));
typedef float f32x4 __attribute__((ext_vector_type(4)));

__device__ __forceinline__ unsigned short f2bf(float v) {
  __hip_bfloat16 h = __float2bfloat16(v);
  return *reinterpret_cast<unsigned short*>(&h);
}

__device__ __forceinline__ void gld_lds16(const unsigned short* g, unsigned short* l) {
  __builtin_amdgcn_global_load_lds((const __attribute__((address_space(1))) void*)g,
                                   (__attribute__((address_space(3))) void*)l,
                                   16, 0, 0);
}

// Stage a 128x32 bf16 tile into LDS [128][32] (linear dest), swizzle on global
// source (rule #21): slot s holds global slot s ^ ((row>>1)&3).
template <int STRIDE, int NT>
__device__ __forceinline__ void stage_tile(const unsigned short* __restrict__ g,
                                           unsigned short* __restrict__ lds, int tid) {
#pragma unroll
  for (int r = 0; r < 512 / NT; ++r) {
    int c = r * NT + tid;
    int row = c >> 2, s = c & 3;
    gld_lds16(g + (size_t)row * STRIDE + ((s ^ ((row >> 1) & 3)) * 8), lds + c * 8);
  }
}

// ---------------- im2col: [B*L, 928] bf16, direct from embedding gather ------
__global__ __launch_bounds__(256) void im2col_kernel(const int* __restrict__ x,
                                                     const float* __restrict__ embedW,
                                                     unsigned short* __restrict__ im) {
  int idx = blockIdx.x * 256 + threadIdx.x;  // < 16384*232
  if (idx >= MC * (KC / 4)) return;
  int row = idx / (KC / 4), g4 = idx - row * (KC / 4);
  int kk = g4 * 4;
  ushort4 o = {0, 0, 0, 0};
  if (kk < 900) {
    int k = kk / 100, e = kk - k * 100;
    int b = row >> 11, l = row & 2047;
    int ls = l + k - 4;
    if (ls >= 0 && ls < L_) {
      const float4 v = *reinterpret_cast<const float4*>(
          &embedW[(size_t)x[b * L_ + ls] * E_ + e]);
      o.x = f2bf(v.x); o.y = f2bf(v.y); o.z = f2bf(v.z); o.w = f2bf(v.w);
    }
  }
  *reinterpret_cast<ushort4*>(&im[(size_t)idx * 4]) = o;
}

// ---------------- pack conv_w [F,E,K] -> wconv [F][k*100+e] bf16 -------------
__global__ __launch_bounds__(256) void wpack_kernel(const float* __restrict__ convw,
                                                    unsigned short* __restrict__ wc) {
  int idx = blockIdx.x * 256 + threadIdx.x;
  if (idx >= F_ * KC) return;
  int f = idx / KC, kk = idx - f * KC;
  float v = 0.f;
  if (kk < 900) {
    int k = kk / 100, e = kk - k * 100;
    v = convw[f * 900 + e * 9 + k];
  }
  wc[idx] = f2bf(v);
}

// ------- pack U_w / final_w to MFMA-fragment layout, padded to 8960 rows -----
// U2[yt][kt][lq][yy(128)][e(8)]: lane(lr,lq) frag (i,kt) reads coalesced 16B.
__global__ __launch_bounds__(256) void ufpack_kernel(const float* __restrict__ Uw,
                                                     const float* __restrict__ Fww,
                                                     unsigned short* __restrict__ U2,
                                                     unsigned short* __restrict__ F2) {
  int idx = blockIdx.x * 256 + threadIdx.x;
  if (idx >= 2 * YP * F_) return;
  int sel = idx / (YP * F_);
  int r = idx - sel * (YP * F_);
  int e = r & 7, t1 = r >> 3;
  int yy = t1 & 127, t2 = t1 >> 7;
  int lq = t2 & 3, t3 = t2 >> 2;
  int kt = t3 & 7, yt = t3 >> 3;
  int y = yt * 128 + yy, f = kt * 32 + lq * 8 + e;
  float v = (y < Y_) ? (sel ? Fww[y * F_ + f] : Uw[y * F_ + f]) : 0.f;
  (sel ? F2 : U2)[r] = f2bf(v);
}

// ---------------- conv GEMM: h[m,n] = tanh(im2col * wconv^T + b) -------------
__global__ __launch_bounds__(256) void conv_gemm(const unsigned short* __restrict__ A,
                                                 const unsigned short* __restrict__ Bt,
                                                 const float* __restrict__ convb,
                                                 unsigned short* __restrict__ hb) {
  __shared__ unsigned short As[3][128 * 32], Bs[3][128 * 32];
  const int mt = blockIdx.x, nt = blockIdx.y, tid = threadIdx.x;
  const unsigned short* Ag = A + (size_t)mt * 128 * KC;
  const unsigned short* Bg = Bt + (size_t)nt * 128 * KC;
  f32x4 acc[4][4] = {};
  const int lane = tid & 63, wv = tid >> 6;
  const int wy = wv >> 1, wx = wv & 1, lr = lane & 15, lq = lane >> 4;
  const int bOff = (lq ^ ((lr >> 1) & 3)) * 8;
  stage_tile<KC, 256>(Ag, As[0], tid);
  stage_tile<KC, 256>(Bg, Bs[0], tid);
  for (int kt = 0; kt < 29; ++kt) {
    const int cur = kt % 3;
    if (kt + 1 < 29) {
      const int nxt = (kt + 1) % 3;
      stage_tile<KC, 256>(Ag + (kt + 1) * 32, As[nxt], tid);
      stage_tile<KC, 256>(Bg + (kt + 1) * 32, Bs[nxt], tid);
      VMCNT(4);
    } else {
      VMCNT(0);
    }
    __builtin_amdgcn_s_barrier();
    CFENCE();
    bf16x8 a[4], bb[4];
#pragma unroll
    for (int i = 0; i < 4; ++i) a[i] = *(const bf16x8*)&As[cur][(wy * 64 + i * 16 + lr) * 32 + bOff];
#pragma unroll
    for (int j = 0; j < 4; ++j) bb[j] = *(const bf16x8*)&Bs[cur][(wx * 64 + j * 16 + lr) * 32 + bOff];
#pragma unroll
    for (int i = 0; i < 4; ++i)
#pragma unroll
      for (int j = 0; j < 4; ++j)
        acc[i][j] = __builtin_amdgcn_mfma_f32_16x16x32_bf16(a[i], bb[j], acc[i][j], 0, 0, 0);
  }
#pragma unroll
  for (int j = 0; j < 4; ++j) {
    const int n = nt * 128 + wx * 64 + j * 16 + lr;
    const float cb = convb[n];
#pragma unroll
    for (int i = 0; i < 4; ++i)
#pragma unroll
      for (int r = 0; r < 4; ++r) {
        const int m = mt * 128 + wy * 64 + i * 16 + lq * 4 + r;
        hb[(size_t)m * F_ + n] = f2bf(tanhf(acc[i][j][r] + cb));
      }
  }
}

// -------- pass 1: scores GEMM (A=U in registers) + exp row-sums --------------
// grid (70 yt, 8 lt2, 8 b). 256 thr, wave 64y x 64l (2x2). 2 blocks/CU.
__global__ __launch_bounds__(256, 2) void scores_v3(const unsigned short* __restrict__ U2,
                                                    const unsigned short* __restrict__ hb,
                                                    float* __restrict__ Spart) {
  __shared__ unsigned short Bs[3][128 * 32];
  __shared__ float rsum[128][2];
  const int yt = blockIdx.x, lt2 = blockIdx.y, b = blockIdx.z, tid = threadIdx.x;
  const int lane = tid & 63, wv = tid >> 6;
  const int wy = wv >> 1, wx = wv & 1, lr = lane & 15, lq = lane >> 4;
  bf16x8 A[4][8];  // [i][kt] in registers (128 VGPR)
  {
    const unsigned short* Up = U2 + (size_t)yt * (8 * 4 * 128 * 8);
#pragma unroll
    for (int i = 0; i < 4; ++i) {
      const int yy = wy * 64 + i * 16 + lr;
#pragma unroll
      for (int kt = 0; kt < 8; ++kt)
        A[i][kt] = *(const bf16x8*)&Up[((kt * 4 + lq) * 128 + yy) * 8];
    }
  }
  const unsigned short* Hg = hb + ((size_t)b * L_ + (size_t)lt2 * 256) * F_;
  const int bOff = (lq ^ ((lr >> 1) & 3)) * 8;
  stage_tile<F_, 256>(Hg, Bs[0], tid);
  f32x4 acc[4][4];
  for (int t = 0; t < 16; ++t) {
    const int kt = t & 7;
    if (t + 1 < 16) {
      stage_tile<F_, 256>(Hg + (size_t)((t + 1) >> 3) * 128 * F_ + ((t + 1) & 7) * 32,
                          Bs[(t + 1) % 3], tid);
      VMCNT(2);
    } else {
      VMCNT(0);
    }
    __builtin_amdgcn_s_barrier();
    CFENCE();
    if (kt == 0) {
#pragma unroll
      for (int i = 0; i < 4; ++i)
#pragma unroll
        for (int j = 0; j < 4; ++j) acc[i][j] = (f32x4){0.f, 0.f, 0.f, 0.f};
    }
    if (t == 8) {  // barrier above made li=0 rsum visible
      if (tid < 128)
        Spart[((size_t)b * YP + yt * 128 + tid) * 16 + lt2 * 2 + 0] =
            rsum[tid][0] + rsum[tid][1];
    }
    const unsigned short* bs = Bs[t % 3];
    bf16x8 bb[4];
#pragma unroll
    for (int j = 0; j < 4; ++j) bb[j] = *(const bf16x8*)&bs[(wx * 64 + j * 16 + lr) * 32 + bOff];
#pragma unroll
    for (int i = 0; i < 4; ++i)
#pragma unroll
      for (int j = 0; j < 4; ++j)
        acc[i][j] = __builtin_amdgcn_mfma_f32_16x16x32_bf16(A[i][kt], bb[j], acc[i][j], 0, 0, 0);
    if (kt == 7) {
#pragma unroll
      for (int i = 0; i < 4; ++i)
#pragma unroll
        for (int r = 0; r < 4; ++r) {
          float rs = 0.f;
#pragma unroll
          for (int j = 0; j < 4; ++j) rs += __expf(acc[i][j][r]);
#pragma unroll
          for (int off = 1; off < 16; off <<= 1) rs += __shfl_xor(rs, off);
          if (lr == 0) rsum[wy * 64 + i * 16 + lq * 4 + r][wx] = rs;
        }
      LGKM0();  // drain rsum ds_writes before next barrier
    }
  }
  __syncthreads();
  if (tid < 128)
    Spart[((size_t)b * YP + yt * 128 + tid) * 16 + lt2 * 2 + 1] = rsum[tid][0] + rsum[tid][1];
}

__global__ __launch_bounds__(256) void sinv_kernel(const float* __restrict__ Spart,
                                                   float* __restrict__ Sinv) {
  int idx = blockIdx.x * 256 + threadIdx.x;
  if (idx >= B_ * YP) return;
  float s = 0.f;
#pragma unroll
  for (int t = 0; t < 16; ++t) s += Spart[(size_t)idx * 16 + t];
  Sinv[idx] = 1.f / s;
}

// ---- pass 2: dual GEMM, A = U+Fw in registers; alpha + yhat numerator -------
// grid (70 yt, 8 b, 8 lz). 256 thr, wave 32y x 64l (4 waves stacked in y).
__global__ __launch_bounds__(256, 2) void dual_v3(const unsigned short* __restrict__ U2,
                                                  const unsigned short* __restrict__ F2,
                                                  const unsigned short* __restrict__ hb,
                                                  const float* __restrict__ Sinv,
                                                  float* __restrict__ alpha,
                                                  float* __restrict__ Npart) {
  __shared__ unsigned short Bs[3][64 * 32];
  const int yt = blockIdx.x, b = blockIdx.y, lz = blockIdx.z, tid = threadIdx.x;
  const int lane = tid & 63, wv = tid >> 6;  // wv = y-stack index
  const int lr = lane & 15, lq = lane >> 4;
  bf16x8 Au[2][8], Af[2][8];  // 128 VGPR
  {
    const unsigned short* Up = U2 + (size_t)yt * (8 * 4 * 128 * 8);
    const unsigned short* Fp = F2 + (size_t)yt * (8 * 4 * 128 * 8);
#pragma unroll
    for (int i = 0; i < 2; ++i) {
      const int yy = wv * 32 + i * 16 + lr;
#pragma unroll
      for (int kt = 0; kt < 8; ++kt) {
        Au[i][kt] = *(const bf16x8*)&Up[((kt * 4 + lq) * 128 + yy) * 8];
        Af[i][kt] = *(const bf16x8*)&Fp[((kt * 4 + lq) * 128 + yy) * 8];
      }
    }
  }
  float si[2][4];
#pragma unroll
  for (int i = 0; i < 2; ++i)
#pragma unroll
    for (int r = 0; r < 4; ++r)
      si[i][r] = Sinv[(size_t)b * YP + yt * 128 + wv * 32 + i * 16 + lq * 4 + r];
  const unsigned short* Hg = hb + ((size_t)b * L_ + (size_t)lz * 256) * F_;
  const int bOff = (lq ^ ((lr >> 1) & 3)) * 8;
  {  // stage first 64x32 tile (4KB = 1 chunk/thread)
    int c = tid, row = c >> 2, s = c & 3;
    gld_lds16(Hg + (size_t)row * F_ + ((s ^ ((row >> 1) & 3)) * 8), Bs[0] + c * 8);
  }
  float nsA[2][4] = {};
  f32x4 accs[2][4], accg[2][4];
  for (int t = 0; t < 32; ++t) {
    const int kt = t & 7, l64 = t >> 3;
    if (t + 1 < 32) {
      int c = tid, row = c >> 2, s = c & 3;
      gld_lds16(Hg + (size_t)(((t + 1) >> 3) * 64 + row) * F_ + ((t + 1) & 7) * 32 +
                    ((s ^ ((row >> 1) & 3)) * 8),
                Bs[(t + 1) % 3] + c * 8);
      VMCNT(1);
    } else {
      VMCNT(0);
    }
    __builtin_amdgcn_s_barrier();
    CFENCE();
    if (kt == 0) {
#pragma unroll
      for (int i = 0; i < 2; ++i)
#pragma unroll
        for (int j = 0; j < 4; ++j) {
          accs[i][j] = (f32x4){0.f, 0.f, 0.f, 0.f};
          accg[i][j] = (f32x4){0.f, 0.f, 0.f, 0.f};
        }
    }
    const unsigned short* bs = Bs[t % 3];
    bf16x8 bb[4];
#pragma unroll
    for (int j = 0; j < 4; ++j) bb[j] = *(const bf16x8*)&bs[(j * 16 + lr) * 32 + bOff];
#pragma unroll
    for (int i = 0; i < 2; ++i)
#pragma unroll
      for (int j = 0; j < 4; ++j) {
        accs[i][j] = __builtin_amdgcn_mfma_f32_16x16x32_bf16(Au[i][kt], bb[j], accs[i][j], 0, 0, 0);
        accg[i][j] = __builtin_amdgcn_mfma_f32_16x16x32_bf16(Af[i][kt], bb[j], accg[i][j], 0, 0, 0);
      }
    if (kt == 7) {
      const int lbase = lz * 256 + l64 * 64;
#pragma unroll
      for (int i = 0; i < 2; ++i) {
        const int y0 = yt * 128 + wv * 32 + i * 16 + lq * 4;
#pragma unroll
        for (int r = 0; r < 4; ++r) {
          float ns = 0.f;
          const float sv = si[i][r];
#pragma unroll
          for (int j = 0; j < 4; ++j) {
            const float av = __expf(accs[i][j][r]) * sv;
            ns += av * accg[i][j][r];
            if (y0 + r < Y_)
              alpha[((size_t)b * Y_ + (y0 + r)) * L_ + lbase + j * 16 + lr] = av;
          }
#pragma unroll
          for (int off = 1; off < 16; off <<= 1) ns += __shfl_xor(ns, off);
          nsA[i][r] += ns;
        }
      }
    }
  }
#pragma unroll
  for (int i = 0; i < 2; ++i)
#pragma unroll
    for (int r = 0; r < 4; ++r)
      if (lr == 0) {
        const int y = yt * 128 + wv * 32 + i * 16 + lq * 4 + r;
        Npart[((size_t)b * YP + y) * 8 + lz] = nsA[i][r];
      }
}

// ---------------- yhat + loss (fused) ---------------------------------------
__global__ __launch_bounds__(256) void yhat_loss_kernel(const float* __restrict__ Npart,
                                                        const float* __restrict__ Fb,
                                                        const float* __restrict__ target,
                                                        float* __restrict__ yhat,
                                                        float* __restrict__ part) {
  __shared__ float red[256];
  float s = 0.f;
  for (int i = blockIdx.x * 256 + threadIdx.x; i < B_ * Y_; i += gridDim.x * 256) {
    int b = i / Y_, y = i - b * Y_;
    float yh = Fb[y];
#pragma unroll
    for (int t = 0; t < 8; ++t) yh += Npart[((size_t)b * YP + y) * 8 + t];
    yhat[i] = yh;
    float tg = target[i];
    s += fmaxf(yh, 0.f) - yh * tg + log1pf(expf(-fabsf(yh)));
  }
  red[threadIdx.x] = s;
  __syncthreads();
  for (int o = 128; o > 0; o >>= 1) {
    if (threadIdx.x < o) red[threadIdx.x] += red[threadIdx.x + o];
    __syncthreads();
  }
  if (threadIdx.x == 0) part[blockIdx.x] = red[0];
}

__global__ __launch_bounds__(128) void loss_final_kernel(const float* __restrict__ part,
                                                         float* __restrict__ loss) {
  __shared__ float red[128];
  red[threadIdx.x] = part[threadIdx.x];
  __syncthreads();
  for (int o = 64; o > 0; o >>= 1) {
    if (threadIdx.x < o) red[threadIdx.x] += red[threadIdx.x + o];
    __syncthreads();
  }
  if (threadIdx.x == 0) loss[0] = red[0] * (1.f / (float)(B_ * Y_));
}

extern "C" void kernel_launch(void* const* d_in, const int* in_sizes, int n_in,
                              void* d_out, int out_size, void* d_ws, size_t ws_size,
                              hipStream_t stream) {
  const int* x = (const int*)d_in[0];
  const float* target = (const float*)d_in[1];
  const float* embedW = (const float*)d_in[2];
  const float* convw = (const float*)d_in[3];
  const float* convb = (const float*)d_in[4];
  const float* Uw = (const float*)d_in[5];
  const float* Fww = (const float*)d_in[6];
  const float* Fb = (const float*)d_in[7];

  float* out = (float*)d_out;
  float* yhat = out;                 // [B*Y] = 71368
  float* loss = out + 71368;         // [1]
  float* alpha = out + 71369;        // [B*Y*L]

  char* w = (char*)d_ws;
  size_t off = 0;
  auto alloc = [&](size_t bytes) -> void* {
    void* p = w + off;
    off += (bytes + 255) & ~(size_t)255;
    return p;
  };
  unsigned short* im2col = (unsigned short*)alloc((size_t)MC * KC * 2);  // 30.4 MB
  unsigned short* wconv = (unsigned short*)alloc((size_t)F_ * KC * 2);   // 0.5 MB
  unsigned short* U2 = (unsigned short*)alloc((size_t)YP * F_ * 2);      // 4.6 MB
  unsigned short* F2 = (unsigned short*)alloc((size_t)YP * F_ * 2);      // 4.6 MB
  unsigned short* hb = (unsigned short*)alloc((size_t)MC * F_ * 2);      // 8.4 MB
  float* Spart = (float*)alloc((size_t)B_ * YP * 16 * 4);                // 4.6 MB
  float* Sinv = (float*)alloc((size_t)B_ * YP * 4);                      // 0.3 MB
  float* Npart = (float*)alloc((size_t)B_ * YP * 8 * 4);                 // 2.3 MB
  float* lpart = (float*)alloc(128 * 4);

  im2col_kernel<<<(MC * (KC / 4) + 255) / 256, 256, 0, stream>>>(x, embedW, im2col);
  wpack_kernel<<<(F_ * KC + 255) / 256, 256, 0, stream>>>(convw, wconv);
  ufpack_kernel<<<(2 * YP * F_ + 255) / 256, 256, 0, stream>>>(Uw, Fww, U2, F2);
  conv_gemm<<<dim3(128, 2), 256, 0, stream>>>(im2col, wconv, convb, hb);
  scores_v3<<<dim3(70, 8, 8), 256, 0, stream>>>(U2, hb, Spart);
  sinv_kernel<<<(B_ * YP + 255) / 256, 256, 0, stream>>>(Spart, Sinv);
  dual_v3<<<dim3(70, 8, 8), 256, 0, stream>>>(U2, F2, hb, Sinv, alpha, Npart);
  yhat_loss_kernel<<<128, 256, 0, stream>>>(Npart, Fb, target, yhat, lpart);
  loss_final_kernel<<<1, 128, 0, stream>>>(lpart, loss);
}